// Round 12
// baseline (319.914 us; speedup 1.0000x reference)
//
#include <hip/hip_runtime.h>
#include <float.h>

// B_=1024 windows, N=64, M=128, H=8, D=32, DIM=256, nW=256
// rel bias index: rel = n - m + 128 in [1,191]
// masks: wi in {0,1} -> mask_left[wi], wi in {254,255} -> mask_right[wi-254]

typedef __attribute__((ext_vector_type(8))) short bf16x8;
typedef __attribute__((ext_vector_type(4))) float f32x4;

static __device__ __forceinline__ unsigned int f2bf(float f) {
    unsigned int u = __float_as_uint(f);
    return (u + 0x7FFFu + ((u >> 16) & 1u)) >> 16;  // RNE
}
static __device__ __forceinline__ unsigned int pack2(float lo, float hi) {
    return f2bf(lo) | (f2bf(hi) << 16);
}

// Pre-swizzled bf16 weight tile images. Each 64x32 W-tile is stored as its exact
// 4 KiB LDS image (Ws[col][k] bf16, byte ^= ((col&3)<<4) within the 64-B row).
// Regions (shorts): q @0, kv @65536, proj @196608.
__device__ unsigned short g_Wt[262144];

__global__ __launch_bounds__(256) void prep_wt(
    const float* __restrict__ q_w, const float* __restrict__ kv_w, const float* __restrict__ proj_w)
{
    const int gid = blockIdx.x * 256 + threadIdx.x;
    int rel, ncs; const float* src;
    if (gid < 65536)       { rel = gid;          src = q_w;    ncs = 256; }
    else if (gid < 196608) { rel = gid - 65536;  src = kv_w;   ncs = 512; }
    else                   { rel = gid - 196608; src = proj_w; ncs = 256; }
    const int tl = rel >> 11, i = rel & 2047;      // tile = ct*8 + ks ; i = short idx in tile
    const int ct = tl >> 3,  ks = tl & 7;
    const int col = i >> 5,  si = i & 31;
    const int kl = ((2 * si) ^ ((col & 3) << 4)) >> 1;   // inverse swizzle (bits 4-5) -> source k
    g_Wt[gid] = (unsigned short)f2bf(src[(ks * 32 + kl) * ncs + ct * 64 + col]);
}

// ---------- pipelined MFMA GEMM (proven R10): C[rows x NC] = A[rows x 256] @ W + bias ----------
template<int NC, int WT_OFF, bool ABF16, bool F32OUT>
__global__ __launch_bounds__(256) void gemm_t(
    const void* __restrict__ Ain, const float* __restrict__ bias, void* __restrict__ Cout)
{
    constexpr int NCT = NC / 64;
    __shared__ __align__(16) unsigned short As[2][4096];
    __shared__ __align__(16) unsigned short Ws[2][2048];

    const int nbx = 8 * NCT;
    const int g = blockIdx.x / nbx, r = blockIdx.x % nbx;
    const int bn = r >> 3, bm = g * 8 + (r & 7);
    const size_t r0 = (size_t)bm * 128;
    const int c0 = bn * 64;

    const int t = threadIdx.x;
    const int wave = t >> 6, lane = t & 63;
    const int lr = lane & 15, hi = lane >> 4;
    const int rw = (wave >> 1) * 64, cw = (wave & 1) * 32;

    const int arow = t >> 1, aseg = t & 1;
    const int aswz = (arow & 3) << 4;
    const int ao0 = (aseg * 32) ^ aswz, ao1 = (aseg * 32 + 16) ^ aswz;

    f32x4 acc[4][2];
    #pragma unroll
    for (int i = 0; i < 4; ++i)
        #pragma unroll
        for (int j = 0; j < 2; ++j) acc[i][j] = (f32x4){0.f, 0.f, 0.f, 0.f};

    float4 ra0, ra1, ra2, ra3;
    uint4  rb0, rb1;
    uint4  rwv;

#define GLOAD(S)                                                                           \
    {                                                                                      \
        rwv = *(const uint4*)(g_Wt + WT_OFF + ((size_t)(bn * 8 + (S)) << 11) + t * 8);     \
        if (ABF16) {                                                                       \
            const unsigned short* asrc = (const unsigned short*)Ain + (r0 + arow) * 256 + (S) * 32 + aseg * 16; \
            rb0 = *(const uint4*)asrc; rb1 = *(const uint4*)(asrc + 8);                    \
        } else {                                                                           \
            const float* asrc = (const float*)Ain + (r0 + arow) * 256 + (S) * 32 + aseg * 16; \
            ra0 = *(const float4*)asrc;       ra1 = *(const float4*)(asrc + 4);            \
            ra2 = *(const float4*)(asrc + 8); ra3 = *(const float4*)(asrc + 12);           \
        }                                                                                  \
    }

#define SWRITE(B)                                                                          \
    {                                                                                      \
        uint4 u0, u1;                                                                      \
        if (ABF16) { u0 = rb0; u1 = rb1; }                                                 \
        else {                                                                             \
            u0 = make_uint4(pack2(ra0.x, ra0.y), pack2(ra0.z, ra0.w),                      \
                            pack2(ra1.x, ra1.y), pack2(ra1.z, ra1.w));                     \
            u1 = make_uint4(pack2(ra2.x, ra2.y), pack2(ra2.z, ra2.w),                      \
                            pack2(ra3.x, ra3.y), pack2(ra3.z, ra3.w));                     \
        }                                                                                  \
        char* ad = (char*)As[B] + arow * 64;                                               \
        *(uint4*)(ad + ao0) = u0; *(uint4*)(ad + ao1) = u1;                                \
        *(uint4*)((char*)Ws[B] + t * 16) = rwv;                                            \
    }

#define COMPUTE(B)                                                                         \
    {                                                                                      \
        const char* Ab = (const char*)As[B];                                               \
        const char* Wb = (const char*)Ws[B];                                               \
        const int ko = (16 * hi) ^ ((lr & 3) << 4);                                        \
        bf16x8 af0 = *(const bf16x8*)(Ab + (rw +      lr) * 64 + ko);                      \
        bf16x8 af1 = *(const bf16x8*)(Ab + (rw + 16 + lr) * 64 + ko);                      \
        bf16x8 af2 = *(const bf16x8*)(Ab + (rw + 32 + lr) * 64 + ko);                      \
        bf16x8 af3 = *(const bf16x8*)(Ab + (rw + 48 + lr) * 64 + ko);                      \
        bf16x8 bg0 = *(const bf16x8*)(Wb + (cw +      lr) * 64 + ko);                      \
        bf16x8 bg1 = *(const bf16x8*)(Wb + (cw + 16 + lr) * 64 + ko);                      \
        acc[0][0] = __builtin_amdgcn_mfma_f32_16x16x32_bf16(af0, bg0, acc[0][0], 0, 0, 0); \
        acc[0][1] = __builtin_amdgcn_mfma_f32_16x16x32_bf16(af0, bg1, acc[0][1], 0, 0, 0); \
        acc[1][0] = __builtin_amdgcn_mfma_f32_16x16x32_bf16(af1, bg0, acc[1][0], 0, 0, 0); \
        acc[1][1] = __builtin_amdgcn_mfma_f32_16x16x32_bf16(af1, bg1, acc[1][1], 0, 0, 0); \
        acc[2][0] = __builtin_amdgcn_mfma_f32_16x16x32_bf16(af2, bg0, acc[2][0], 0, 0, 0); \
        acc[2][1] = __builtin_amdgcn_mfma_f32_16x16x32_bf16(af2, bg1, acc[2][1], 0, 0, 0); \
        acc[3][0] = __builtin_amdgcn_mfma_f32_16x16x32_bf16(af3, bg0, acc[3][0], 0, 0, 0); \
        acc[3][1] = __builtin_amdgcn_mfma_f32_16x16x32_bf16(af3, bg1, acc[3][1], 0, 0, 0); \
    }

    GLOAD(0); SWRITE(0); __syncthreads();

    #pragma unroll 8
    for (int s = 0; s < 8; ++s) {
        if (s < 7) GLOAD(s + 1);
        COMPUTE(s & 1);
        if (s < 7) {
            SWRITE((s + 1) & 1);
            __syncthreads();
        }
    }

#undef GLOAD
#undef SWRITE
#undef COMPUTE

    #pragma unroll
    for (int i = 0; i < 4; ++i) {
        #pragma unroll
        for (int bj = 0; bj < 2; ++bj) {
            const int col = c0 + cw + bj * 16 + lr;
            const float bb = bias[col];
            #pragma unroll
            for (int q = 0; q < 4; ++q) {
                const size_t row = r0 + rw + i * 16 + 4 * hi + q;
                const float val = acc[i][bj][q] + bb;
                if (F32OUT) ((float*)Cout)[row * NC + col] = val;
                else        ((unsigned short*)Cout)[row * NC + col] = (unsigned short)f2bf(val);
            }
        }
    }
}

// ---------- fused kv-projection + attention: one block per WINDOW ----------
// Stages x_ tile bf16 once; per head computes K/V via MFMA from pre-swizzled g_Wt
// slabs, then runs the proven QK^T/softmax/PV pipeline. Writes bf16 attn output
// into the q buffer region (block-local rows -> race-free).
__global__ __launch_bounds__(256) void attn_kv(
    const unsigned short* __restrict__ qbf, const float* __restrict__ x_,
    const float* __restrict__ kv_bias, const float* __restrict__ bias_table,
    const int* __restrict__ mask_left, const int* __restrict__ mask_right,
    unsigned short* __restrict__ aout)
{
    __shared__ __align__(16) unsigned short XL[128 * 256];  // x_ tile [m][k], 512B rows, swz ((m&7)<<4)
    __shared__ __align__(16) unsigned short W2s[8 * 2048];  // [ks][32 Kcols | 32 Vcols][32k] images, swz ((col&3)<<4)
    __shared__ __align__(16) unsigned short Kn[128 * 32];   // [m][d] natural
    __shared__ __align__(16) unsigned short Vt[32 * 128];   // [d][m], swz ((d&7)<<4)
    __shared__ __align__(16) unsigned short Pn[64 * 128];   // [n][m], swz ((n&7)<<4)
    __shared__ __align__(16) unsigned short Qn[64 * 32];    // [n][d] natural
    __shared__ float ballT[8 * 192];                        // bias table [h][rel]
    __shared__ float kvb[512];                              // kv bias

    const int w = blockIdx.x;
    const int t = threadIdx.x;
    const int wave = t >> 6, lane = t & 63;
    const int lr = lane & 15, hi = lane >> 4;
    const int n0w = wave * 16;    // attn-phase wave rows (16 q-rows)
    const int rw4 = wave * 32;    // kv-proj wave rows (32 m-rows)

    for (int i = t; i < 1536; i += 256) {
        const int hh = i / 192, rr = i - hh * 192;
        ballT[i] = bias_table[rr * 8 + hh];
    }
    kvb[t] = kv_bias[t];
    kvb[t + 256] = kv_bias[t + 256];

    {   // stage x_ tile -> XL bf16 swizzled (row = t>>1, half = t&1 covers k 0..127/128..255)
        const int row = t >> 1, half = t & 1;
        const float* src = x_ + ((size_t)(w * 128 + row)) * 256 + half * 128;
        char* dst = (char*)XL + row * 512;
        const int swz = (row & 7) << 4;
        #pragma unroll 2
        for (int u = 0; u < 8; ++u) {
            const float4 a = *(const float4*)(src + u * 16);
            const float4 b = *(const float4*)(src + u * 16 + 4);
            const float4 c = *(const float4*)(src + u * 16 + 8);
            const float4 d = *(const float4*)(src + u * 16 + 12);
            const int base = half * 256 + u * 32;
            *(uint4*)(dst + (base ^ swz)) =
                make_uint4(pack2(a.x, a.y), pack2(a.z, a.w), pack2(b.x, b.y), pack2(b.z, b.w));
            *(uint4*)(dst + ((base + 16) ^ swz)) =
                make_uint4(pack2(c.x, c.y), pack2(c.z, c.w), pack2(d.x, d.y), pack2(d.z, d.w));
        }
    }

    const int wi = w & 255;
    const int* mbase = nullptr;
    if (wi < 2) mbase = mask_left + wi * (64 * 128);
    else if (wi >= 254) mbase = mask_right + (wi - 254) * (64 * 128);

    const float scale = 0.17677669529663687f;  // 32^-0.5

    for (int h = 0; h < 8; ++h) {
        __syncthreads();   // B1: XL visible (h=0); prior head's Kn/Vt/Qn/W2s reads complete

        {   // stage W2s: K-slab (tile ct=h/2, col-half h&1) + V-slab (ct=4+h/2)
            const uint4* wsrc = (const uint4*)(g_Wt + 65536);
            uint4* wdst = (uint4*)W2s;
            const int ctK = h >> 1, half = h & 1;
            #pragma unroll
            for (int u = 0; u < 8; ++u) {
                const int idx = t + u * 256;          // 16B units, 0..2047
                const int ks = idx >> 8;
                const int kvh = (idx >> 7) & 1;       // 0:K 1:V
                const int off = idx & 127;
                const int ct = kvh ? (4 + ctK) : ctK;
                wdst[idx] = wsrc[(ct * 8 + ks) * 256 + half * 128 + off];
            }
        }
        {   // stage Q head-slice: [64][32]
            const int n = t >> 2, dq = t & 3;
            const uint4 v = *(const uint4*)(qbf + ((size_t)(w * 64 + n)) * 256 + h * 32 + dq * 8);
            *(uint4*)((char*)Qn + n * 64 + dq * 16) = v;
        }
        __syncthreads();   // B2: W2s/Qn published; prior Kn/Vt reads already done at B1

        // ---- kv-proj: [128 m] x [64 cols: K d0..31 | V d0..31], K=256 ----
        f32x4 kacc[2][4];
        #pragma unroll
        for (int i = 0; i < 2; ++i)
            #pragma unroll
            for (int j = 0; j < 4; ++j) kacc[i][j] = (f32x4){0.f, 0.f, 0.f, 0.f};

        {
            const int swzX = (lr & 7) << 4;
            const int ko2  = (16 * hi) ^ ((lr & 3) << 4);
            #pragma unroll
            for (int ks = 0; ks < 8; ++ks) {
                const int koX = (ks * 64 + 16 * hi) ^ swzX;
                const bf16x8 af0 = *(const bf16x8*)((char*)XL + (rw4 +      lr) * 512 + koX);
                const bf16x8 af1 = *(const bf16x8*)((char*)XL + (rw4 + 16 + lr) * 512 + koX);
                const char* wb = (const char*)W2s + ks * 4096;
                #pragma unroll
                for (int j = 0; j < 4; ++j) {
                    const bf16x8 bfr = *(const bf16x8*)(wb + (j * 16 + lr) * 64 + ko2);
                    kacc[0][j] = __builtin_amdgcn_mfma_f32_16x16x32_bf16(af0, bfr, kacc[0][j], 0, 0, 0);
                    kacc[1][j] = __builtin_amdgcn_mfma_f32_16x16x32_bf16(af1, bfr, kacc[1][j], 0, 0, 0);
                }
            }
        }
        // K epilogue: j=0,1 -> Kn[m][d] (pair even/odd lr -> u32 stores)
        #pragma unroll
        for (int i = 0; i < 2; ++i) {
            #pragma unroll
            for (int j = 0; j < 2; ++j) {
                const int d = j * 16 + lr;
                const float bb = kvb[h * 32 + d];
                #pragma unroll
                for (int q = 0; q < 4; ++q) {
                    const float kv_ = kacc[i][j][q] + bb;
                    const float po = __shfl_xor(kv_, 1);
                    if (!(lane & 1)) {
                        const int m = rw4 + i * 16 + 4 * hi + q;
                        *(unsigned int*)((char*)Kn + m * 64 + 2 * d) = f2bf(kv_) | (f2bf(po) << 16);
                    }
                }
            }
            // V epilogue: j=2,3 -> Vt[d][m] swizzled (4 consecutive m -> uint2 store)
            #pragma unroll
            for (int j = 2; j < 4; ++j) {
                const int d = (j - 2) * 16 + lr;
                const float bb = kvb[256 + h * 32 + d];
                const int m0 = rw4 + i * 16 + 4 * hi;
                const unsigned int lo = pack2(kacc[i][j][0] + bb, kacc[i][j][1] + bb);
                const unsigned int h2 = pack2(kacc[i][j][2] + bb, kacc[i][j][3] + bb);
                *(uint2*)((char*)Vt + d * 256 + ((2 * m0) ^ ((d & 7) << 4))) = make_uint2(lo, h2);
            }
        }
        __syncthreads();   // B3: Kn/Vt published

        // ---- S = Q K^T : wave handles rows n0w..n0w+15, all 128 cols ----
        const bf16x8 qa = *(const bf16x8*)((char*)Qn + (n0w + lr) * 64 + 16 * hi);
        f32x4 sacc[8];
        #pragma unroll
        for (int mj = 0; mj < 8; ++mj) {
            sacc[mj] = (f32x4){0.f, 0.f, 0.f, 0.f};
            const bf16x8 kb = *(const bf16x8*)((char*)Kn + (mj * 16 + lr) * 64 + 16 * hi);
            sacc[mj] = __builtin_amdgcn_mfma_f32_16x16x32_bf16(qa, kb, sacc[mj], 0, 0, 0);
        }

        const float* bh = ballT + h * 192;
        #pragma unroll
        for (int mj = 0; mj < 8; ++mj) {
            const int m = 16 * mj + lr;
            #pragma unroll
            for (int q = 0; q < 4; ++q) {
                const int n = n0w + 4 * hi + q;
                sacc[mj][q] = fmaf(sacc[mj][q], scale, bh[n - m + 128]);
            }
        }
        if (mbase) {
            #pragma unroll
            for (int mj = 0; mj < 8; ++mj) {
                const int m = 16 * mj + lr;
                #pragma unroll
                for (int q = 0; q < 4; ++q) {
                    const int n = n0w + 4 * hi + q;
                    if (mbase[n * 128 + m] == 1) sacc[mj][q] = -FLT_MAX;
                }
            }
        }

        float inv[4];
        #pragma unroll
        for (int q = 0; q < 4; ++q) {
            float mx = sacc[0][q];
            #pragma unroll
            for (int mj = 1; mj < 8; ++mj) mx = fmaxf(mx, sacc[mj][q]);
            mx = fmaxf(mx, __shfl_xor(mx, 1));
            mx = fmaxf(mx, __shfl_xor(mx, 2));
            mx = fmaxf(mx, __shfl_xor(mx, 4));
            mx = fmaxf(mx, __shfl_xor(mx, 8));
            float sm = 0.f;
            #pragma unroll
            for (int mj = 0; mj < 8; ++mj) {
                sacc[mj][q] = __expf(sacc[mj][q] - mx);
                sm += sacc[mj][q];
            }
            sm += __shfl_xor(sm, 1);
            sm += __shfl_xor(sm, 2);
            sm += __shfl_xor(sm, 4);
            sm += __shfl_xor(sm, 8);
            inv[q] = 1.0f / sm;
        }

        #pragma unroll
        for (int mj = 0; mj < 8; ++mj) {
            #pragma unroll
            for (int q = 0; q < 4; ++q) {
                const float pv = sacc[mj][q];
                const float po = __shfl_xor(pv, 1);
                if (!(lane & 1)) {
                    const int n = n0w + 4 * hi + q;
                    const int m = 16 * mj + lr;   // even
                    *(unsigned int*)((char*)Pn + n * 256 + ((2 * m) ^ ((n & 7) << 4))) =
                        f2bf(pv) | (f2bf(po) << 16);
                }
            }
        }
        // no barrier: each wave reads only its own Pn rows

        f32x4 oacc[2];
        oacc[0] = (f32x4){0.f, 0.f, 0.f, 0.f};
        oacc[1] = (f32x4){0.f, 0.f, 0.f, 0.f};
        const int nA = n0w + lr;
        const int swzA = (nA & 7) << 4;
        #pragma unroll
        for (int kk = 0; kk < 4; ++kk) {
            const bf16x8 pa = *(const bf16x8*)((char*)Pn + nA * 256 + ((64 * kk + 16 * hi) ^ swzA));
            #pragma unroll
            for (int j = 0; j < 2; ++j) {
                const int d = j * 16 + lr;
                const bf16x8 vb = *(const bf16x8*)((char*)Vt + d * 256 + ((64 * kk + 16 * hi) ^ ((d & 7) << 4)));
                oacc[j] = __builtin_amdgcn_mfma_f32_16x16x32_bf16(pa, vb, oacc[j], 0, 0, 0);
            }
        }
        #pragma unroll
        for (int j = 0; j < 2; ++j) {
            #pragma unroll
            for (int q = 0; q < 4; ++q) {
                const int n = n0w + 4 * hi + q;
                aout[((size_t)(w * 64 + n)) * 256 + h * 32 + j * 16 + lr] =
                    (unsigned short)f2bf(oacc[j][q] * inv[q]);
            }
        }
    }
}

extern "C" void kernel_launch(void* const* d_in, const int* in_sizes, int n_in,
                              void* d_out, int out_size, void* d_ws, size_t ws_size,
                              hipStream_t stream)
{
    const float* x      = (const float*)d_in[0];   // (1024,64,256) f32
    const float* x_     = (const float*)d_in[1];   // (1024,128,256) f32
    const int*   mask_l = (const int*)d_in[2];
    const int*   mask_r = (const int*)d_in[3];
    const float* q_w    = (const float*)d_in[5];
    const float* q_b    = (const float*)d_in[6];
    const float* kv_w   = (const float*)d_in[7];
    const float* kv_b   = (const float*)d_in[8];
    const float* proj_w = (const float*)d_in[9];
    const float* proj_b = (const float*)d_in[10];
    const float* bias_t = (const float*)d_in[11];  // (192,8)

    // ws: qbf bf16 [65536][256] (32 MiB; overwritten in-place with bf16 attn-out)
    unsigned short* qbf = (unsigned short*)d_ws;
    float* out = (float*)d_out;

    prep_wt<<<1024, 256, 0, stream>>>(q_w, kv_w, proj_w);
    gemm_t<256, 0,      false, false><<<2048, 256, 0, stream>>>(x, q_b, qbf);
    attn_kv<<<1024, 256, 0, stream>>>(qbf, x_, kv_b, bias_t, mask_l, mask_r, qbf);
    gemm_t<256, 196608, true,  true ><<<2048, 256, 0, stream>>>(qbf, proj_b, out);
}

// Round 13
// 265.353 us; speedup vs baseline: 1.2056x; 1.2056x over previous
//
#include <hip/hip_runtime.h>
#include <float.h>

// B_=1024 windows, N=64, M=128, H=8, D=32, DIM=256, nW=256
// rel bias index: rel = n - m + 128 in [1,191]
// masks: wi in {0,1} -> mask_left[wi], wi in {254,255} -> mask_right[wi-254]

typedef __attribute__((ext_vector_type(8))) short bf16x8;
typedef __attribute__((ext_vector_type(4))) float f32x4;

static __device__ __forceinline__ unsigned int f2bf(float f) {
    unsigned int u = __float_as_uint(f);
    return (u + 0x7FFFu + ((u >> 16) & 1u)) >> 16;  // RNE
}
static __device__ __forceinline__ unsigned int pack2(float lo, float hi) {
    return f2bf(lo) | (f2bf(hi) << 16);
}

// Transposed bf16 weights: [col][k], q @0 (256x256), kv @65536 (512x256), proj @196608 (256x256)
__device__ unsigned short g_Wt[262144];

__global__ __launch_bounds__(256) void prep_wt(
    const float* __restrict__ q_w, const float* __restrict__ kv_w, const float* __restrict__ proj_w)
{
    const int b = blockIdx.x, k = threadIdx.x;
    float v; unsigned short* dst;
    if (b < 256)      { v = q_w[k * 256 + b];            dst = g_Wt + b * 256; }
    else if (b < 768) { v = kv_w[k * 512 + (b - 256)];   dst = g_Wt + 65536 + (b - 256) * 256; }
    else              { v = proj_w[k * 256 + (b - 768)]; dst = g_Wt + 196608 + (b - 768) * 256; }
    dst[k] = (unsigned short)f2bf(v);
}

// ---------- double-buffered MFMA GEMM (R7-proven): C[rows x NC] = A[rows x 256] @ W + bias ----------
// Tile 128x128, BK=64, LDS 64KB -> 2 blocks/CU. 512 threads = 8 waves (2x4), wave tile 64x32.
// VSPLIT (kv only): col tiles 0..1 (K half) stored natural [row][256]; col tiles 2..3 (V half)
// stored TRANSPOSED vws[w][vcol][m] via uint2 stores (4 consecutive m per C-fragment column).
template<int NC, int WT_OFF, bool ABF16, bool F32OUT, bool VSPLIT>
__global__ __launch_bounds__(512) void gemm_db(
    const void* __restrict__ Ain, const float* __restrict__ bias, void* __restrict__ Cout,
    unsigned short* __restrict__ Vout)
{
    constexpr int NBN = NC / 128;
    __shared__ __align__(16) unsigned short As[2][128 * 64];
    __shared__ __align__(16) unsigned short Ws[2][128 * 64];

    const int nbx = 8 * NBN;
    const int g = blockIdx.x / nbx, r = blockIdx.x % nbx;
    const int bn = r >> 3, bm = g * 8 + (r & 7);
    const size_t r0 = (size_t)bm * 128;
    const int c0 = bn * 128;

    const int t = threadIdx.x;
    const int wave = t >> 6, lane = t & 63;
    const int lr = lane & 15, hi = lane >> 4;
    const int rw = (wave >> 2) * 64, cw = (wave & 3) * 32;
    const int srow = t >> 2, sks = (t & 3) * 16;
    const int aswz = (srow & 7) << 4;
    const int so1 = (2 * sks) ^ aswz, so2 = (2 * sks + 16) ^ aswz;

    f32x4 acc[4][2];
    #pragma unroll
    for (int i = 0; i < 4; ++i)
        #pragma unroll
        for (int j = 0; j < 2; ++j) acc[i][j] = (f32x4){0.f, 0.f, 0.f, 0.f};

    float4 fA0, fA1, fA2, fA3;
    uint4  sA0, sA1;
    uint4  sW0, sW1;

#define STAGE_LOAD(K0)                                                                     \
    {                                                                                      \
        const unsigned short* wsrc = g_Wt + WT_OFF + (size_t)(c0 + srow) * 256 + (K0) + sks; \
        sW0 = *(const uint4*)wsrc; sW1 = *(const uint4*)(wsrc + 8);                        \
        if (ABF16) {                                                                       \
            const unsigned short* asrc = (const unsigned short*)Ain + (r0 + srow) * 256 + (K0) + sks; \
            sA0 = *(const uint4*)asrc; sA1 = *(const uint4*)(asrc + 8);                    \
        } else {                                                                           \
            const float* asrc = (const float*)Ain + (r0 + srow) * 256 + (K0) + sks;        \
            fA0 = *(const float4*)asrc;       fA1 = *(const float4*)(asrc + 4);            \
            fA2 = *(const float4*)(asrc + 8); fA3 = *(const float4*)(asrc + 12);           \
        }                                                                                  \
    }

#define STAGE_WRITE(B)                                                                     \
    {                                                                                      \
        char* ad = (char*)As[B] + srow * 128;                                              \
        char* wd = (char*)Ws[B] + srow * 128;                                              \
        uint4 u0, u1;                                                                      \
        if (ABF16) { u0 = sA0; u1 = sA1; }                                                 \
        else {                                                                             \
            u0 = make_uint4(pack2(fA0.x, fA0.y), pack2(fA0.z, fA0.w),                      \
                            pack2(fA1.x, fA1.y), pack2(fA1.z, fA1.w));                     \
            u1 = make_uint4(pack2(fA2.x, fA2.y), pack2(fA2.z, fA2.w),                      \
                            pack2(fA3.x, fA3.y), pack2(fA3.z, fA3.w));                     \
        }                                                                                  \
        *(uint4*)(ad + so1) = u0; *(uint4*)(ad + so2) = u1;                                \
        *(uint4*)(wd + so1) = sW0; *(uint4*)(wd + so2) = sW1;                              \
    }

#define COMPUTE(B)                                                                         \
    {                                                                                      \
        const char* Ab = (const char*)As[B];                                               \
        const char* Wb = (const char*)Ws[B];                                               \
        const int swzr = (lr & 7) << 4;                                                    \
        _Pragma("unroll")                                                                  \
        for (int kk = 0; kk < 2; ++kk) {                                                   \
            const int ko = (kk * 64 + hi * 16) ^ swzr;                                     \
            bf16x8 af[4], bf[2];                                                           \
            _Pragma("unroll")                                                              \
            for (int i = 0; i < 4; ++i)                                                    \
                af[i] = *(const bf16x8*)(Ab + (rw + i * 16 + lr) * 128 + ko);              \
            _Pragma("unroll")                                                              \
            for (int j = 0; j < 2; ++j)                                                    \
                bf[j] = *(const bf16x8*)(Wb + (cw + j * 16 + lr) * 128 + ko);              \
            _Pragma("unroll")                                                              \
            for (int i = 0; i < 4; ++i)                                                    \
                _Pragma("unroll")                                                          \
                for (int j = 0; j < 2; ++j)                                                \
                    acc[i][j] = __builtin_amdgcn_mfma_f32_16x16x32_bf16(af[i], bf[j], acc[i][j], 0, 0, 0); \
        }                                                                                  \
    }

    STAGE_LOAD(0); STAGE_WRITE(0); __syncthreads();
    STAGE_LOAD(64);
    COMPUTE(0);
    STAGE_WRITE(1);
    STAGE_LOAD(128);
    __syncthreads();
    COMPUTE(1);
    STAGE_WRITE(0);
    STAGE_LOAD(192);
    __syncthreads();
    COMPUTE(0);
    STAGE_WRITE(1);
    __syncthreads();
    COMPUTE(1);

#undef STAGE_LOAD
#undef STAGE_WRITE
#undef COMPUTE

    // epilogue
    #pragma unroll
    for (int i = 0; i < 4; ++i) {
        #pragma unroll
        for (int bj = 0; bj < 2; ++bj) {
            const int col = c0 + cw + bj * 16 + lr;
            const float bb = bias[col];
            if (VSPLIT && c0 >= 256) {
                // V half: transposed store vws[w][vcol][m], 4 consecutive m -> uint2
                const int vcol = col - 256;
                const int m0 = rw + i * 16 + 4 * hi;
                const unsigned int lo = pack2(acc[i][bj][0] + bb, acc[i][bj][1] + bb);
                const unsigned int h2 = pack2(acc[i][bj][2] + bb, acc[i][bj][3] + bb);
                *(uint2*)(Vout + (size_t)bm * 32768 + vcol * 128 + m0) = make_uint2(lo, h2);
            } else if (VSPLIT) {
                // K half: natural, row stride 256
                #pragma unroll
                for (int q = 0; q < 4; ++q) {
                    const size_t row = r0 + rw + i * 16 + 4 * hi + q;
                    ((unsigned short*)Cout)[row * 256 + col] = (unsigned short)f2bf(acc[i][bj][q] + bb);
                }
            } else {
                #pragma unroll
                for (int q = 0; q < 4; ++q) {
                    const size_t row = r0 + rw + i * 16 + 4 * hi + q;
                    const float val = acc[i][bj][q] + bb;
                    if (F32OUT) ((float*)Cout)[row * NC + col] = val;
                    else        ((unsigned short*)Cout)[row * NC + col] = (unsigned short)f2bf(val);
                }
            }
        }
    }
}

// ---------- fused MFMA attention: one block per WINDOW, loop over 8 heads ----------
// K read natural from kws [w*128+m][256]; V read pre-transposed from vws [w][vcol][m].
// Writes bf16 attn output back into the q buffer region (block-local rows -> race-free).
__global__ __launch_bounds__(256) void attn_fused(
    const unsigned short* __restrict__ qbf, const unsigned short* __restrict__ kws,
    const unsigned short* __restrict__ vws, const float* __restrict__ bias_table,
    const int* __restrict__ mask_left, const int* __restrict__ mask_right,
    unsigned short* __restrict__ aout)
{
    __shared__ __align__(16) unsigned short Qn[64 * 32];    // [n][d] natural
    __shared__ __align__(16) unsigned short Kn[128 * 32];   // [m][d] natural
    __shared__ __align__(16) unsigned short Vt[32 * 128];   // [d][m], swizzled ^((d&7)<<4)
    __shared__ __align__(16) unsigned short Pn[64 * 128];   // [n][m], swizzled ^((n&7)<<4)
    __shared__ float ballT[8 * 192];                        // bias table [h][rel]

    const int w = blockIdx.x;
    const int t = threadIdx.x;
    const int wave = t >> 6, lane = t & 63;
    const int lr = lane & 15, hi = lane >> 4;
    const int n0w = wave * 16;

    for (int i = t; i < 1536; i += 256) {
        const int hh = i / 192, rr = i - hh * 192;
        ballT[i] = bias_table[rr * 8 + hh];
    }

    const int wi = w & 255;
    const int* mbase = nullptr;
    if (wi < 2) mbase = mask_left + wi * (64 * 128);
    else if (wi >= 254) mbase = mask_right + (wi - 254) * (64 * 128);

    const float scale = 0.17677669529663687f;  // 32^-0.5

    for (int h = 0; h < 8; ++h) {
        __syncthreads();   // prior iteration's LDS reads complete (and ballT before first use)
        {   // stage Q head-slice: [64][32]
            const int n = t >> 2, dq = t & 3;
            const uint4 v = *(const uint4*)(qbf + ((size_t)(w * 64 + n)) * 256 + h * 32 + dq * 8);
            *(uint4*)((char*)Qn + n * 64 + dq * 16) = v;
        }
        #pragma unroll
        for (int i = 0; i < 2; ++i) {   // stage K: [128][32] natural
            const int m = (t >> 2) + 64 * i, dq = t & 3;
            const uint4 v = *(const uint4*)(kws + ((size_t)(w * 128 + m)) * 256 + h * 32 + dq * 8);
            *(uint4*)((char*)Kn + m * 64 + dq * 16) = v;
        }
        {   // stage V: contiguous 8KB from vws -> swizzled Vt (pure uint4 copies)
            const unsigned short* vsrc = vws + (size_t)w * 32768 + h * 32 * 128;
            #pragma unroll
            for (int i = 0; i < 2; ++i) {
                const int u = t + i * 256;        // 16B units, 0..511
                const int d = u >> 4, mseg = u & 15;
                const uint4 vv = *(const uint4*)(vsrc + d * 128 + mseg * 8);
                *(uint4*)((char*)Vt + d * 256 + ((mseg * 16) ^ ((d & 7) << 4))) = vv;
            }
        }
        __syncthreads();

        // S = Q K^T : wave handles rows n0w..n0w+15, all 128 cols
        const bf16x8 qa = *(const bf16x8*)((char*)Qn + (n0w + lr) * 64 + 16 * hi);
        f32x4 sacc[8];
        #pragma unroll
        for (int mj = 0; mj < 8; ++mj) {
            sacc[mj] = (f32x4){0.f, 0.f, 0.f, 0.f};
            const bf16x8 kb = *(const bf16x8*)((char*)Kn + (mj * 16 + lr) * 64 + 16 * hi);
            sacc[mj] = __builtin_amdgcn_mfma_f32_16x16x32_bf16(qa, kb, sacc[mj], 0, 0, 0);
        }

        // epilogue on C-layout: row n = n0w + 4*hi + q, col m = 16*mj + lr
        const float* bh = ballT + h * 192;
        #pragma unroll
        for (int mj = 0; mj < 8; ++mj) {
            const int m = 16 * mj + lr;
            #pragma unroll
            for (int q = 0; q < 4; ++q) {
                const int n = n0w + 4 * hi + q;
                sacc[mj][q] = fmaf(sacc[mj][q], scale, bh[n - m + 128]);
            }
        }
        if (mbase) {
            #pragma unroll
            for (int mj = 0; mj < 8; ++mj) {
                const int m = 16 * mj + lr;
                #pragma unroll
                for (int q = 0; q < 4; ++q) {
                    const int n = n0w + 4 * hi + q;
                    if (mbase[n * 128 + m] == 1) sacc[mj][q] = -FLT_MAX;
                }
            }
        }

        // softmax over m (per row): row lives in 16 lanes sharing hi -> shfl_xor 1,2,4,8
        float inv[4];
        #pragma unroll
        for (int q = 0; q < 4; ++q) {
            float mx = sacc[0][q];
            #pragma unroll
            for (int mj = 1; mj < 8; ++mj) mx = fmaxf(mx, sacc[mj][q]);
            mx = fmaxf(mx, __shfl_xor(mx, 1));
            mx = fmaxf(mx, __shfl_xor(mx, 2));
            mx = fmaxf(mx, __shfl_xor(mx, 4));
            mx = fmaxf(mx, __shfl_xor(mx, 8));
            float sm = 0.f;
            #pragma unroll
            for (int mj = 0; mj < 8; ++mj) {
                sacc[mj][q] = __expf(sacc[mj][q] - mx);
                sm += sacc[mj][q];
            }
            sm += __shfl_xor(sm, 1);
            sm += __shfl_xor(sm, 2);
            sm += __shfl_xor(sm, 4);
            sm += __shfl_xor(sm, 8);
            inv[q] = 1.0f / sm;
        }

        // write unnormalized P bf16 to Pn (pair even/odd lanes -> u32 stores); wave-local rows
        #pragma unroll
        for (int mj = 0; mj < 8; ++mj) {
            #pragma unroll
            for (int q = 0; q < 4; ++q) {
                const float pv = sacc[mj][q];
                const float po = __shfl_xor(pv, 1);
                if (!(lane & 1)) {
                    const int n = n0w + 4 * hi + q;
                    const int m = 16 * mj + lr;   // even
                    *(unsigned int*)((char*)Pn + n * 256 + ((2 * m) ^ ((n & 7) << 4))) =
                        f2bf(pv) | (f2bf(po) << 16);
                }
            }
        }
        // no barrier needed: each wave reads only its own Pn rows

        // O = P V : rows n0w..+15, cols d 0..31 (j=0,1)
        f32x4 oacc[2];
        oacc[0] = (f32x4){0.f, 0.f, 0.f, 0.f};
        oacc[1] = (f32x4){0.f, 0.f, 0.f, 0.f};
        const int nA = n0w + lr;                 // A-frag row
        const int swzA = (nA & 7) << 4;
        #pragma unroll
        for (int kk = 0; kk < 4; ++kk) {
            const bf16x8 pa = *(const bf16x8*)((char*)Pn + nA * 256 + ((64 * kk + 16 * hi) ^ swzA));
            #pragma unroll
            for (int j = 0; j < 2; ++j) {
                const int d = j * 16 + lr;
                const bf16x8 vb = *(const bf16x8*)((char*)Vt + d * 256 + ((64 * kk + 16 * hi) ^ ((d & 7) << 4)));
                oacc[j] = __builtin_amdgcn_mfma_f32_16x16x32_bf16(pa, vb, oacc[j], 0, 0, 0);
            }
        }
        // store bf16 into aout (the q region): row n = n0w+4*hi+q, col h*32 + j*16 + lr
        #pragma unroll
        for (int j = 0; j < 2; ++j) {
            #pragma unroll
            for (int q = 0; q < 4; ++q) {
                const int n = n0w + 4 * hi + q;
                aout[((size_t)(w * 64 + n)) * 256 + h * 32 + j * 16 + lr] =
                    (unsigned short)f2bf(oacc[j][q] * inv[q]);
            }
        }
    }
}

extern "C" void kernel_launch(void* const* d_in, const int* in_sizes, int n_in,
                              void* d_out, int out_size, void* d_ws, size_t ws_size,
                              hipStream_t stream)
{
    const float* x      = (const float*)d_in[0];   // (1024,64,256) f32
    const float* x_     = (const float*)d_in[1];   // (1024,128,256) f32
    const int*   mask_l = (const int*)d_in[2];
    const int*   mask_r = (const int*)d_in[3];
    const float* q_w    = (const float*)d_in[5];
    const float* q_b    = (const float*)d_in[6];
    const float* kv_w   = (const float*)d_in[7];
    const float* kv_b   = (const float*)d_in[8];
    const float* proj_w = (const float*)d_in[9];
    const float* proj_b = (const float*)d_in[10];
    const float* bias_t = (const float*)d_in[11];  // (192,8)

    // ws: qbf [65536][256] bf16 (32 MiB, later overwritten with attn-out)
    //   | kws [131072][256] bf16 (64 MiB, K natural)
    //   | vws [1024][256][128] bf16 (64 MiB, V transposed per window)
    unsigned short* qbf = (unsigned short*)d_ws;
    unsigned short* kws = qbf + (size_t)65536 * 256;
    unsigned short* vws = kws + (size_t)131072 * 256;
    float* out = (float*)d_out;

    prep_wt<<<1024, 256, 0, stream>>>(q_w, kv_w, proj_w);
    gemm_db<256, 0,      false, false, false><<<1024, 512, 0, stream>>>(x,  q_b,  qbf, nullptr);
    gemm_db<512, 65536,  false, false, true ><<<4096, 512, 0, stream>>>(x_, kv_b, kws, vws);
    attn_fused<<<1024, 256, 0, stream>>>(qbf, kws, vws, bias_t, mask_l, mask_r, qbf);
    gemm_db<256, 196608, true,  true,  false><<<1024, 512, 0, stream>>>(qbf, proj_b, out, nullptr);
}